// Round 5
// baseline (311.223 us; speedup 1.0000x reference)
//
#include <hip/hip_runtime.h>

#define BATCH 8
#define HH 64
#define WW 64
#define CC 256
#define KK 512
#define CH 7
#define CW 7
#define HW 4096            // HH*WW
#define CROPS_ELEMS (BATCH * KK * CH * CW * CC)   // 51,380,224
#define BOXES_ELEMS (BATCH * KK * 4)              // 16,384
#define JOBS 3584          // KK*CH jobs (roi, crop-row) per batch

using f4 = __attribute__((ext_vector_type(4))) float;

// ---------------------------------------------------------------------------
// Kernel 1 (unchanged, stable since round 0): per-batch top-512 by RANK
// SELECTION. key = (ordered_uint(score) << 12) | (4095 - index) is unique per
// element, so rank(i) = #{keys > key_i} is the exact descending-sort position
// with jax.lax.top_k tie semantics (equal score -> lower index first).
// ---------------------------------------------------------------------------
__global__ __launch_bounds__(256) void rank_topk_kernel(
    const float* __restrict__ scores,      // [B, 4096]
    const float* __restrict__ boxes,       // [B, 4096, 4]
    float* __restrict__ boxes_out,         // [B, 512, 4]
    float* __restrict__ idx_out)           // [B, 512] (as float values)
{
    __shared__ unsigned long long keys[HW];   // 32 KB
    __shared__ int cnt[64];

    const int b     = blockIdx.x & 7;         // batch -> XCD
    const int chunk = blockIdx.x >> 3;        // which 64-element slice we rank
    const int tid   = threadIdx.x;

    for (int i = tid; i < HW; i += 256) {
        unsigned int u = __float_as_uint(scores[b * HW + i]);
        u = (u & 0x80000000u) ? ~u : (u | 0x80000000u);
        keys[i] = ((unsigned long long)u << 12) |
                  (unsigned long long)(HW - 1 - i);
    }
    if (tid < 64) cnt[tid] = 0;
    __syncthreads();

    const int e_local = tid & 63;
    const int e       = chunk * 64 + e_local;
    const unsigned long long mine = keys[e];
    const int seg = (tid >> 6) * (HW / 4);

    int c = 0;
    #pragma unroll 8
    for (int j = 0; j < HW / 4; ++j) {
        c += (keys[seg + j] > mine) ? 1 : 0;
    }
    atomicAdd(&cnt[e_local], c);
    __syncthreads();

    if (tid < 64) {
        const int r = cnt[tid];                 // exact descending rank
        if (r < KK) {
            const int i = chunk * 64 + tid;     // original flat index
            idx_out[b * KK + r] = (float)i;
            const float* bp = boxes + (size_t)(b * HW + i) * 4;
            float* op = boxes_out + (size_t)(b * KK + r) * 4;
            op[0] = bp[0]; op[1] = bp[1]; op[2] = bp[2]; op[3] = bp[3];
        }
    }
}

// ---------------------------------------------------------------------------
// Kernel 1.5 (NEW, v6): y-sort the 3584 (roi, crop-row) jobs of each batch.
// PERFORMANCE-ONLY reordering: crops processes jobs in ascending sample-y
// order so the ~1024 concurrently-resident jobs per XCD touch an ~18-row
// (~1.2 MiB) sliding band of the 4.0 MiB fm slice instead of random rows —
// promoting the 822 MB of corner gathers from L3 tier to L2 hits.
// Output positions are unchanged; perm is bijective (unique u64 keys with
// job-index tiebreak -> exact ranks), so results are bit-identical.
// Same rank-selection machinery as topk: 56 chunks x 64 jobs per batch.
// The y key here needs NO reference-exact rounding (ordering heuristic only).
// ---------------------------------------------------------------------------
__global__ __launch_bounds__(256) void sort_jobs_kernel(
    const float* __restrict__ sboxes,      // [B, 512, 4]
    int* __restrict__ perm)                // [B, 3584]
{
    __shared__ unsigned long long keys[JOBS];   // 28 KB
    __shared__ int cnt[64];

    const int b     = blockIdx.x & 7;         // batch -> XCD
    const int chunk = blockIdx.x >> 3;        // 0..55
    const int tid   = threadIdx.x;

    for (int j = tid; j < JOBS; j += 256) {
        const int n  = j / 7;
        const int iy = j % 7;
        const f4 box = *(const f4*)(sboxes + (size_t)(b * KK + n) * 4);
        // sample y in [0,63]; boxes are uniform [0,1) so y >= 0 and finite ->
        // raw float bits are monotone as unsigned.
        const float y = (box[0] + ((float)iy / 6.0f) * (box[2] - box[0])) * 63.0f;
        keys[j] = ((unsigned long long)__float_as_uint(y) << 12) |
                  (unsigned long long)j;
    }
    if (tid < 64) cnt[tid] = 0;
    __syncthreads();

    const int e = chunk * 64 + (tid & 63);
    const unsigned long long mine = keys[e];
    const int seg = (tid >> 6) * (JOBS / 4);

    int c = 0;
    #pragma unroll 8
    for (int j = 0; j < JOBS / 4; ++j) {
        c += (keys[seg + j] < mine) ? 1 : 0;    // ascending-y rank
    }
    atomicAdd(&cnt[tid & 63], c);
    __syncthreads();

    if (tid < 64) {
        perm[b * JOBS + cnt[tid]] = chunk * 64 + tid;
    }
}

// ---------------------------------------------------------------------------
// Kernel 2 (v6): crop_and_resize — v5 row-per-wave structure UNCHANGED except
// the wave's job comes from perm[] (y-sorted order) instead of linear order.
//
// Evidence trail (rounds 1-4): v5 cut waves 7x / VALU ~5x / MLP 4->28 with
// ZERO time change vs v1 -> crops is purely memory-system-bound. Time fits
// "gathers served at L3 tier, serialized with the store stream" (~100 µs vs
// ~40 µs floor). This round changes ONLY the processing order to make the
// per-XCD gather working set L2-resident (sliding ~1.2 MiB y-band).
//
// Coordinate math mirrors the reference's elementwise rounding exactly (no
// FMA contraction): floor() boundaries are discontinuous under the
// clip-after-floor edge semantics. x-columns' i/6.0f are constant-folded at
// exact IEEE rounding after unrolling (== reference arange/6).
// ---------------------------------------------------------------------------
__global__ __launch_bounds__(256, 2) void crops_kernel(
    const float* __restrict__ fm,          // [B, 64, 64, 256]
    const float* __restrict__ sboxes,      // [B, 512, 4]
    const int* __restrict__ perm,          // [B, 3584] y-sorted job ids
    float* __restrict__ out)               // [B, 512, 7, 7, 256]
{
    const int b     = blockIdx.x & 7;                  // batch -> XCD
    const int inner = blockIdx.x >> 3;                 // 0..895 within batch
    const int p     = inner * 4 + (threadIdx.x >> 6);  // sorted position
    const int lane  = threadIdx.x & 63;

    const int wib = perm[b * JOBS + p];    // actual job (wave-uniform load)
    const int n  = wib / 7;                // roi within batch
    const int iy = wib % 7;                // crop row
    const int bn = b * KK + n;

    const f4 box = *(const f4*)(sboxes + (size_t)bn * 4);
    const float y1 = box[0], x1 = box[1], y2 = box[2], x2 = box[3];

    // y chain: once per wave (the only runtime fdiv left).
    const float fy = (float)iy / 6.0f;
    const float y = __fmul_rn(__fadd_rn(y1, __fmul_rn(fy, __fsub_rn(y2, y1))), 63.0f);
    const float y0f = floorf(y);
    const float wy  = y - y0f;
    const float owy = 1.0f - wy;
    int y0 = (int)y0f; y0 = min(max(y0, 0), HH - 1);
    const int y1i = min(y0 + 1, HH - 1);

    const int c0 = lane * 4;
    const float* fb  = fm + (size_t)b * (HH * WW * CC) + c0;
    const float* py0 = fb + (size_t)y0  * (WW * CC);
    const float* py1 = fb + (size_t)y1i * (WW * CC);
    float* op = out + ((size_t)bn * 49 + iy * 7) * CC + c0;

    const float xd = __fsub_rn(x2, x1);

    #pragma unroll
    for (int ix = 0; ix < CW; ++ix) {
        // fx is a compile-time constant (exact IEEE i/6.0f) after unrolling.
        const float fx = (float)ix / 6.0f;
        const float x = __fmul_rn(__fadd_rn(x1, __fmul_rn(fx, xd)), 63.0f);
        const float x0f = floorf(x);
        const float wx  = x - x0f;
        int x0 = (int)x0f; x0 = min(max(x0, 0), WW - 1);
        const int x1i = min(x0 + 1, WW - 1);

        const f4 v00 = *(const f4*)(py0 + x0  * CC);
        const f4 v01 = *(const f4*)(py0 + x1i * CC);
        const f4 v10 = *(const f4*)(py1 + x0  * CC);
        const f4 v11 = *(const f4*)(py1 + x1i * CC);

        const float owx = 1.0f - wx;
        f4 r;
        #pragma unroll
        for (int k = 0; k < 4; ++k) {
            float t  = v00[k] * owx + v01[k] * wx;
            float bo = v10[k] * owx + v11[k] * wx;
            r[k] = t * owy + bo * wy;
        }
        __builtin_nontemporal_store(r, (f4*)(op + ix * CC));
    }
}

extern "C" void kernel_launch(void* const* d_in, const int* in_sizes, int n_in,
                              void* d_out, int out_size, void* d_ws, size_t ws_size,
                              hipStream_t stream) {
    const float* feature_map = (const float*)d_in[0];   // 8*64*64*256
    const float* boxes       = (const float*)d_in[1];   // 8*64*64*4
    const float* rpn_loss    = (const float*)d_in[2];   // 8*64*64

    float* crops_out = (float*)d_out;                       // 51,380,224
    float* boxes_out = crops_out + CROPS_ELEMS;             // 16,384
    float* idx_out   = boxes_out + BOXES_ELEMS;             // 4,096
    int*   perm      = (int*)d_ws;                          // 8*3584 ints (112 KB)

    rank_topk_kernel<<<BATCH * 64, 256, 0, stream>>>(rpn_loss, boxes, boxes_out, idx_out);

    // y-sort the (roi, crop-row) jobs of each batch (perf-only reordering).
    sort_jobs_kernel<<<BATCH * (JOBS / 64), 256, 0, stream>>>(boxes_out, perm);

    // 8 batches * 896 blocks; 4 waves/block; wave = y-sorted (roi, crop-row).
    const int total_waves = BATCH * KK * CH;                // 28,672
    crops_kernel<<<total_waves / 4, 256, 0, stream>>>(feature_map, boxes_out, perm, crops_out);
}

// Round 8
// 271.974 us; speedup vs baseline: 1.1443x; 1.1443x over previous
//
#include <hip/hip_runtime.h>

#define BATCH 8
#define HH 64
#define WW 64
#define CC 256
#define KK 512
#define CH 7
#define CW 7
#define HW 4096            // HH*WW
#define CROPS_ELEMS (BATCH * KK * CH * CW * CC)   // 51,380,224
#define BOXES_ELEMS (BATCH * KK * 4)              // 16,384

using f4 = __attribute__((ext_vector_type(4))) float;

// ---------------------------------------------------------------------------
// Kernel 1 (unchanged, stable since round 0): per-batch top-512 by RANK
// SELECTION. key = (ordered_uint(score) << 12) | (4095 - index) is unique per
// element, so rank(i) = #{keys > key_i} is the exact descending-sort position
// with jax.lax.top_k tie semantics (equal score -> lower index first).
// ---------------------------------------------------------------------------
__global__ __launch_bounds__(256) void rank_topk_kernel(
    const float* __restrict__ scores,      // [B, 4096]
    const float* __restrict__ boxes,       // [B, 4096, 4]
    float* __restrict__ boxes_out,         // [B, 512, 4]
    float* __restrict__ idx_out)           // [B, 512] (as float values)
{
    __shared__ unsigned long long keys[HW];   // 32 KB
    __shared__ int cnt[64];

    const int b     = blockIdx.x & 7;         // batch -> XCD
    const int chunk = blockIdx.x >> 3;        // which 64-element slice we rank
    const int tid   = threadIdx.x;

    for (int i = tid; i < HW; i += 256) {
        unsigned int u = __float_as_uint(scores[b * HW + i]);
        u = (u & 0x80000000u) ? ~u : (u | 0x80000000u);
        keys[i] = ((unsigned long long)u << 12) |
                  (unsigned long long)(HW - 1 - i);
    }
    if (tid < 64) cnt[tid] = 0;
    __syncthreads();

    const int e_local = tid & 63;
    const int e       = chunk * 64 + e_local;
    const unsigned long long mine = keys[e];
    const int seg = (tid >> 6) * (HW / 4);

    int c = 0;
    #pragma unroll 8
    for (int j = 0; j < HW / 4; ++j) {
        c += (keys[seg + j] > mine) ? 1 : 0;
    }
    atomicAdd(&cnt[e_local], c);
    __syncthreads();

    if (tid < 64) {
        const int r = cnt[tid];                 // exact descending rank
        if (r < KK) {
            const int i = chunk * 64 + tid;     // original flat index
            idx_out[b * KK + r] = (float)i;
            const float* bp = boxes + (size_t)(b * HW + i) * 4;
            float* op = boxes_out + (size_t)(b * KK + r) * 4;
            op[0] = bp[0]; op[1] = bp[1]; op[2] = bp[2]; op[3] = bp[3];
        }
    }
}

// ---------------------------------------------------------------------------
// Kernel 2 (v9): crop_and_resize — v5 row-per-wave body, ONE variable changed:
// PLAIN stores instead of __builtin_nontemporal_store.
//
// Post-mortem trail (rounds 0-7): crops ~120 µs vs ~35-40 µs floor, and
// EXACTLY insensitive to wave count / VALU / MLP / store scope / job order
// (v1 == v5 at 271.3) -> a hard throughput ceiling shared by all versions.
// The one inherited, never-A/B'd variable is the NT store. Evidence FOR the
// NT-store theory: the harness's own fillBufferAligned sustains 6.5 TB/s
// with plain stores (822 MB / 125 µs); if `nt` bypasses L2's write-combine /
// streaming path and drains at ~2 TB/s, the 205.6 MB output alone is
// ~100 µs — matching the unexplained gap and explaining every null result.
// L2 write-allocate was already shown harmless to the read side (round-2 sc1
// probe neutral). Grid-sync fusion abandoned: cooperative launch no-ops under
// graph capture (r6), manual spin barrier hangs the container (r7).
//
// Coordinate math mirrors the reference's elementwise rounding exactly (no
// FMA contraction): floor() boundaries are discontinuous under the
// clip-after-floor edge semantics. x-columns' i/6.0f constant-fold at exact
// IEEE rounding after unrolling (== reference arange/6).
// ---------------------------------------------------------------------------
__global__ __launch_bounds__(256, 2) void crops_kernel(
    const float* __restrict__ fm,          // [B, 64, 64, 256]
    const float* __restrict__ sboxes,      // [B, 512, 4]
    float* __restrict__ out)               // [B, 512, 7, 7, 256]
{
    const int b     = blockIdx.x & 7;                  // batch -> XCD
    const int inner = blockIdx.x >> 3;                 // 0..895 within batch
    const int wib   = inner * 4 + (threadIdx.x >> 6);  // 0..3583: (n, iy)
    const int lane  = threadIdx.x & 63;

    const int n  = wib / 7;                // roi within batch
    const int iy = wib % 7;                // crop row
    const int bn = b * KK + n;

    const f4 box = *(const f4*)(sboxes + (size_t)bn * 4);
    const float y1 = box[0], x1 = box[1], y2 = box[2], x2 = box[3];

    // y chain: once per wave (the only runtime fdiv left).
    const float fy = (float)iy / 6.0f;
    const float y = __fmul_rn(__fadd_rn(y1, __fmul_rn(fy, __fsub_rn(y2, y1))), 63.0f);
    const float y0f = floorf(y);
    const float wy  = y - y0f;
    const float owy = 1.0f - wy;
    int y0 = (int)y0f; y0 = min(max(y0, 0), HH - 1);
    const int y1i = min(y0 + 1, HH - 1);

    const int c0 = lane * 4;
    const float* fb  = fm + (size_t)b * (HH * WW * CC) + c0;
    const float* py0 = fb + (size_t)y0  * (WW * CC);
    const float* py1 = fb + (size_t)y1i * (WW * CC);
    float* op = out + ((size_t)bn * 49 + iy * 7) * CC + c0;

    const float xd = __fsub_rn(x2, x1);

    #pragma unroll
    for (int ix = 0; ix < CW; ++ix) {
        // fx is a compile-time constant (exact IEEE i/6.0f) after unrolling.
        const float fx = (float)ix / 6.0f;
        const float x = __fmul_rn(__fadd_rn(x1, __fmul_rn(fx, xd)), 63.0f);
        const float x0f = floorf(x);
        const float wx  = x - x0f;
        int x0 = (int)x0f; x0 = min(max(x0, 0), WW - 1);
        const int x1i = min(x0 + 1, WW - 1);

        const f4 v00 = *(const f4*)(py0 + x0  * CC);
        const f4 v01 = *(const f4*)(py0 + x1i * CC);
        const f4 v10 = *(const f4*)(py1 + x0  * CC);
        const f4 v11 = *(const f4*)(py1 + x1i * CC);

        const float owx = 1.0f - wx;
        f4 r;
        #pragma unroll
        for (int k = 0; k < 4; ++k) {
            float t  = v00[k] * owx + v01[k] * wx;
            float bo = v10[k] * owx + v11[k] * wx;
            r[k] = t * owy + bo * wy;
        }
        // PLAIN store (the round-8 A/B variable): goes through L2's
        // write-combine path like the 6.5 TB/s harness fill.
        *(f4*)(op + ix * CC) = r;
    }
}

extern "C" void kernel_launch(void* const* d_in, const int* in_sizes, int n_in,
                              void* d_out, int out_size, void* d_ws, size_t ws_size,
                              hipStream_t stream) {
    const float* feature_map = (const float*)d_in[0];   // 8*64*64*256
    const float* boxes       = (const float*)d_in[1];   // 8*64*64*4
    const float* rpn_loss    = (const float*)d_in[2];   // 8*64*64

    float* crops_out = (float*)d_out;                       // 51,380,224
    float* boxes_out = crops_out + CROPS_ELEMS;             // 16,384
    float* idx_out   = boxes_out + BOXES_ELEMS;             // 4,096

    rank_topk_kernel<<<BATCH * 64, 256, 0, stream>>>(rpn_loss, boxes, boxes_out, idx_out);

    // 8 batches * 896 blocks; 4 waves/block; wave = (roi, crop-row).
    const int total_waves = BATCH * KK * CH;                // 28,672
    crops_kernel<<<total_waves / 4, 256, 0, stream>>>(feature_map, boxes_out, crops_out);
}